// Round 11
// baseline (234.896 us; speedup 1.0000x reference)
//
#include <hip/hip_runtime.h>
#include <math.h>

// Problem constants (fixed by setup_inputs)
#define BB   256
#define DIN  2048
#define DD   512
#define CC   1000
#define NN   50000
#define FILTER_K 100
#define SLOT 512           // per-class capacity; max real ~90 old + <=256 new
#define CSTRIDE 16         // one counter per 64B cacheline (atomic contention)

#define SK1  32            // split-K for z = x@Wf  (klen 64)
#define SKP  8             // split-K for p = z@Wc^T (klen 64)
#define NBLK 512           // megaA grid: 2 blocks/CU, guaranteed resident
#define NGRP 8             // barrier arrival groups (two-level barrier)
#define GSZ  (NBLK / NGRP) // 64 blocks per group

// ---------------- workspace layout (float elements) ----------------
#define Z_OFF     0                          // z:     [256][512]
#define CNT_OFF   (Z_OFF + BB*DD)            // cnt:   [1024*16] int (strided)
#define BAR_BASE  16384                      // int offset within cnt region
#define ARR_IDX(g)   (BAR_BASE + (g)*1024)          // arrival counters, 8 pages
#define GFLG_IDX(g)  (BAR_BASE + (8+(g))*1024)      // per-group flags, 8 pages
#define GLBC_IDX     (BAR_BASE + 16*1024)           // global counter
#define GLBF_IDX     (BAR_BASE + 17*1024)           // global flag
#define CNT_INTS  (16384 + 20*1024)          // 36864 ints memset'd
#define EI_OFF    (CNT_OFF + CNT_INTS)       // ei:    [1000][512] float2 (ent,idx)
#define WN_OFF    (EI_OFF + CC*SLOT*2)       // wn:    [1000][512]
#define ZP_OFF    (WN_OFF + CC*DD)           // zpart: [32][256][512]
#define PP_OFF    (ZP_OFF + SK1*BB*DD)       // ppart: [8][256][1000]

#define SMEM_F 3712        // 14848 B shared overlay (max phase = class_weights 3588)

// ---- MALL-coherent (write-through) stores for cross-phase intermediates ----
typedef float f32x4 __attribute__((ext_vector_type(4)));
typedef float f32x2 __attribute__((ext_vector_type(2)));

__device__ __forceinline__ void st_wc4(float* p, float4 v) {
  f32x4 w = {v.x, v.y, v.z, v.w};
  asm volatile("global_store_dwordx4 %0, %1, off sc0 sc1" :: "v"(p), "v"(w) : "memory");
}
__device__ __forceinline__ void st_wc2(float* p, float a, float b) {
  f32x2 w = {a, b};
  asm volatile("global_store_dwordx2 %0, %1, off sc0 sc1" :: "v"(p), "v"(w) : "memory");
}
__device__ __forceinline__ void st_wc1(float* p, float a) {
  asm volatile("global_store_dword %0, %1, off sc0 sc1" :: "v"(p), "v"(a) : "memory");
}
// coherent 8B load (ei is written in two phases; bypass L1/L2)
__device__ __forceinline__ float2 ld_cv2(const float2* p) {
  unsigned long long r = __hip_atomic_load((const unsigned long long*)p,
      __ATOMIC_RELAXED, __HIP_MEMORY_SCOPE_AGENT);
  float2 o;
  o.x = __uint_as_float((unsigned)(r & 0xffffffffULL));
  o.y = __uint_as_float((unsigned)(r >> 32));
  return o;
}
__device__ __forceinline__ int ld_ci(const int* p) {
  return __hip_atomic_load(p, __ATOMIC_RELAXED, __HIP_MEMORY_SCOPE_AGENT);
}

// ---- device-wide sense barrier (used only inside megaA, epochs 1..3) ----
__device__ __forceinline__ void gsync(int* cnt, int epoch, int grp, bool leader) {
  asm volatile("s_waitcnt vmcnt(0) lgkmcnt(0)" ::: "memory");
  __syncthreads();
  if (threadIdx.x == 0) {
    int t = __hip_atomic_fetch_add(&cnt[ARR_IDX(grp)], 1, __ATOMIC_RELAXED,
                                   __HIP_MEMORY_SCOPE_AGENT);
    if (t == epoch * GSZ - 1) {
      int u = __hip_atomic_fetch_add(&cnt[GLBC_IDX], 1, __ATOMIC_RELAXED,
                                     __HIP_MEMORY_SCOPE_AGENT);
      if (u == epoch * NGRP - 1)
        __hip_atomic_store(&cnt[GLBF_IDX], epoch, __ATOMIC_RELAXED,
                           __HIP_MEMORY_SCOPE_AGENT);
    }
    if (leader) {
      while (__hip_atomic_load(&cnt[GLBF_IDX], __ATOMIC_RELAXED,
                               __HIP_MEMORY_SCOPE_AGENT) < epoch)
        __builtin_amdgcn_s_sleep(4);
      __hip_atomic_store(&cnt[GFLG_IDX(grp)], epoch, __ATOMIC_RELAXED,
                         __HIP_MEMORY_SCOPE_AGENT);
    } else {
      while (__hip_atomic_load(&cnt[GFLG_IDX(grp)], __ATOMIC_RELAXED,
                               __HIP_MEMORY_SCOPE_AGENT) < epoch)
        __builtin_amdgcn_s_sleep(8);
    }
  }
  __syncthreads();
}

// ---- per-class select-K + normalized row-sum + column norm (R8-verified) ----
__device__ __forceinline__ void do_class(
    int c, int tid, float* smem, const float* supports_in, const float* z,
    const float2* ei, const int* cnt, float* wn) {
  int*   sel = (int*)smem;                       // [512]
  float* se  = smem + SLOT;                      // [512]
  int*   si  = (int*)(smem + 2*SLOT);            // [512]
  float (*part)[DD] = (float(*)[DD])(smem + 3*SLOT);  // [4][512]
  float* tot = smem + 3*SLOT + 4*DD;             // [4]
  const int lane = tid & 63, wid = tid >> 6;
  int n = ld_ci(&cnt[c * CSTRIDE]); if (n > SLOT) n = SLOT;

  int seln;
  if (n <= FILTER_K) {
    seln = n;
    for (int i = tid; i < n; i += 256)
      sel[i] = __float_as_int(ld_cv2(&ei[(size_t)c * SLOT + i]).y);
  } else {
    for (int i = tid; i < SLOT; i += 256) {
      if (i < n) {
        float2 pr = ld_cv2(&ei[(size_t)c * SLOT + i]);
        se[i] = pr.x; si[i] = __float_as_int(pr.y);
      } else { se[i] = INFINITY; si[i] = 0x7fffffff; }
    }
    __syncthreads();
    for (int k = 2; k <= SLOT; k <<= 1)
      for (int j = k >> 1; j > 0; j >>= 1) {
        for (int i = tid; i < SLOT; i += 256) {
          int ixj = i ^ j;
          if (ixj > i) {
            bool up = ((i & k) == 0);
            float e1 = se[i], e2 = se[ixj];
            int i1 = si[i], i2 = si[ixj];
            bool gt = (e1 > e2) || (e1 == e2 && i1 > i2);
            if (gt == up) { se[i] = e2; se[ixj] = e1; si[i] = i2; si[ixj] = i1; }
          }
        }
        __syncthreads();
      }
    seln = FILTER_K;
    for (int i = tid; i < FILTER_K; i += 256) sel[i] = si[i];
  }
  __syncthreads();
  const int seln_pad = (seln + 15) & ~15;
  if (seln > 0)
    for (int i = seln + tid; i < seln_pad; i += 256) sel[i] = sel[0];
  __syncthreads();

  float4 a0 = make_float4(0.f, 0.f, 0.f, 0.f), a1 = a0;
  for (int t = wid * 4; t < seln_pad; t += 16) {
    float4 u0[4], u1[4]; float s[4];
#pragma unroll
    for (int j = 0; j < 4; ++j) {
      int r = sel[t + j];
      const float4* p4 = (const float4*)((r < NN)
          ? supports_in + (size_t)r * DD : z + (size_t)(r - NN) * DD);
      u0[j] = p4[lane * 2]; u1[j] = p4[lane * 2 + 1];
    }
#pragma unroll
    for (int j = 0; j < 4; ++j)
      s[j] = u0[j].x * u0[j].x + u0[j].y * u0[j].y + u0[j].z * u0[j].z
           + u0[j].w * u0[j].w + u1[j].x * u1[j].x + u1[j].y * u1[j].y
           + u1[j].z * u1[j].z + u1[j].w * u1[j].w;
#pragma unroll
    for (int o = 1; o < 64; o <<= 1) {
#pragma unroll
      for (int j = 0; j < 4; ++j) s[j] += __shfl_xor(s[j], o, 64);
    }
#pragma unroll
    for (int j = 0; j < 4; ++j) {
      float sc = (t + j < seln) ? 1.0f / fmaxf(sqrtf(s[j]), 1e-12f) : 0.f;
      a0.x += u0[j].x * sc; a0.y += u0[j].y * sc;
      a0.z += u0[j].z * sc; a0.w += u0[j].w * sc;
      a1.x += u1[j].x * sc; a1.y += u1[j].y * sc;
      a1.z += u1[j].z * sc; a1.w += u1[j].w * sc;
    }
  }

  *(float4*)&part[wid][lane * 8] = a0;
  *(float4*)&part[wid][lane * 8 + 4] = a1;
  __syncthreads();
  const int d = tid * 2;
  float wx = part[0][d] + part[1][d] + part[2][d] + part[3][d];
  float wy = part[0][d + 1] + part[1][d + 1] + part[2][d + 1] + part[3][d + 1];
  float ss = wx * wx + wy * wy;
#pragma unroll
  for (int o = 1; o < 64; o <<= 1) ss += __shfl_xor(ss, o, 64);
  if (lane == 0) tot[wid] = ss;
  __syncthreads();
  float S = tot[0] + tot[1] + tot[2] + tot[3];
  float sc = 1.0f / fmaxf(sqrtf(S), 1e-12f);
  st_wc2(wn + (size_t)c * DD + 2 * tid, wx * sc, wy * sc);
}

// ---- 64x64 split-K A@B^T tile body (phase 3) ----
__device__ __forceinline__ void gemm_abt_tile(
    const float* __restrict__ A, const float* __restrict__ Bm,
    float* __restrict__ Cb, float* smem, int tid, int m0, int n0, int k0) {
  float (*As)[68] = (float(*)[68])smem;
  float (*Bs)[68] = (float(*)[68])(smem + 16 * 68);
  const int ar = tid >> 2, ac = (tid & 3) * 4;
  const int tm = (tid >> 4) * 4, tn = (tid & 15) * 4;
  float acc[4][4] = {};
  float4 av = *(const float4*)&A[(size_t)(m0 + ar) * DD + k0 + ac];
  float4 bv = make_float4(0.f, 0.f, 0.f, 0.f);
  if (n0 + ar < CC) bv = *(const float4*)&Bm[(size_t)(n0 + ar) * DD + k0 + ac];
  for (int kk = 0; kk < 64; kk += 16) {
    __syncthreads();
    As[ac + 0][ar] = av.x; As[ac + 1][ar] = av.y;
    As[ac + 2][ar] = av.z; As[ac + 3][ar] = av.w;
    Bs[ac + 0][ar] = bv.x; Bs[ac + 1][ar] = bv.y;
    Bs[ac + 2][ar] = bv.z; Bs[ac + 3][ar] = bv.w;
    __syncthreads();
    if (kk + 16 < 64) {
      av = *(const float4*)&A[(size_t)(m0 + ar) * DD + k0 + kk + 16 + ac];
      if (n0 + ar < CC)
        bv = *(const float4*)&Bm[(size_t)(n0 + ar) * DD + k0 + kk + 16 + ac];
    }
#pragma unroll
    for (int q = 0; q < 16; ++q) {
      float4 a = *(const float4*)&As[q][tm];
      float4 b = *(const float4*)&Bs[q][tn];
      float aa[4] = {a.x, a.y, a.z, a.w};
      float bb[4] = {b.x, b.y, b.z, b.w};
#pragma unroll
      for (int i = 0; i < 4; ++i)
#pragma unroll
        for (int j = 0; j < 4; ++j) acc[i][j] += aa[i] * bb[j];
    }
  }
#pragma unroll
  for (int i = 0; i < 4; ++i) {
    int n = n0 + tn;
    if (n + 3 < CC) {
      st_wc4(&Cb[(size_t)(m0 + tm + i) * CC + n],
             make_float4(acc[i][0], acc[i][1], acc[i][2], acc[i][3]));
    } else {
#pragma unroll
      for (int j = 0; j < 4; ++j)
        if (n + j < CC) st_wc1(&Cb[(size_t)(m0 + tm + i) * CC + n + j], acc[i][j]);
    }
  }
}

// ========== kernel A: phases 1-4 (+ full-occupancy MALL warm, phase 2.5) ==========
__global__ __launch_bounds__(256, 2) void megaA(
    const float* x, const float* Wf, const float* Wc, const float* bc,
    const float* supports_in, const float* ent_in, const int* labels_idx,
    float* ws) {
  __shared__ __align__(16) float smem[SMEM_F];
  float*  z     = ws + Z_OFF;
  int*    cnt   = (int*)(ws + CNT_OFF);
  float2* ei    = (float2*)(ws + EI_OFF);
  float*  zpart = ws + ZP_OFF;
  float*  ppart = ws + PP_OFF;
  const int bid = blockIdx.x, tid = threadIdx.x;
  const int grp = bid >> 6;
  const bool leader = (bid & 63) == 0;

  // ---- Phase 1: zpart = x@Wf split-K, ALL 512 blocks (SK1=32, klen=64) ----
  {
    float (*As)[68]  = (float(*)[68])smem;
    float (*Bs)[132] = (float(*)[132])(smem + 16 * 68);
    const int m0 = ((bid >> 2) & 3) * 64;
    const int n0 = (bid & 3) * 128;
    const int k0 = (bid >> 4) * 64;
    const int ar = tid >> 2, ac = (tid & 3) * 4;
    const int br = tid >> 4, bcn = (tid & 15) * 8;
    const int tm = (tid >> 4) * 4, tn = (tid & 15) * 4;
    float acc[4][8] = {};
    float4 av  = *(const float4*)&x[(size_t)(m0 + ar) * DIN + k0 + ac];
    float4 bv0 = *(const float4*)&Wf[(size_t)(k0 + br) * DD + n0 + bcn];
    float4 bv1 = *(const float4*)&Wf[(size_t)(k0 + br) * DD + n0 + bcn + 4];
    for (int kk = 0; kk < 64; kk += 16) {
      __syncthreads();
      As[ac + 0][ar] = av.x; As[ac + 1][ar] = av.y;
      As[ac + 2][ar] = av.z; As[ac + 3][ar] = av.w;
      *(float4*)&Bs[br][bcn] = bv0;
      *(float4*)&Bs[br][bcn + 4] = bv1;
      __syncthreads();
      if (kk + 16 < 64) {
        av  = *(const float4*)&x[(size_t)(m0 + ar) * DIN + k0 + kk + 16 + ac];
        bv0 = *(const float4*)&Wf[(size_t)(k0 + kk + 16 + br) * DD + n0 + bcn];
        bv1 = *(const float4*)&Wf[(size_t)(k0 + kk + 16 + br) * DD + n0 + bcn + 4];
      }
#pragma unroll
      for (int q = 0; q < 16; ++q) {
        float4 a  = *(const float4*)&As[q][tm];
        float4 b0 = *(const float4*)&Bs[q][tn];
        float4 b1 = *(const float4*)&Bs[q][tn + 64];
        float aa[4] = {a.x, a.y, a.z, a.w};
        float bb[8] = {b0.x, b0.y, b0.z, b0.w, b1.x, b1.y, b1.z, b1.w};
#pragma unroll
        for (int i = 0; i < 4; ++i)
#pragma unroll
          for (int j = 0; j < 8; ++j) acc[i][j] += aa[i] * bb[j];
      }
    }
    float* Cb = zpart + (size_t)(bid >> 4) * BB * DD;
#pragma unroll
    for (int i = 0; i < 4; ++i) {
      st_wc4(&Cb[(size_t)(m0 + tm + i) * DD + n0 + tn],
             make_float4(acc[i][0], acc[i][1], acc[i][2], acc[i][3]));
      st_wc4(&Cb[(size_t)(m0 + tm + i) * DD + n0 + 64 + tn],
             make_float4(acc[i][4], acc[i][5], acc[i][6], acc[i][7]));
    }
  }
  gsync(cnt, 1, grp, leader);

  // ---- Phase 2: z reduce (0..127) | old-row scatter (128..323) ----
  if (bid < 128) {
    const int n4 = BB * DD / 4;
    int i = bid * 256 + tid;
    if (i < n4) {
      const float4* p4 = (const float4*)zpart;
      float4 a = p4[i];
#pragma unroll
      for (int s = 1; s < SK1; ++s) {
        float4 b = p4[(size_t)s * n4 + i];
        a.x += b.x; a.y += b.y; a.z += b.z; a.w += b.w;
      }
      st_wc4(z + 4 * (size_t)i, a);
    }
  } else if (bid < 324) {
    int m = (bid - 128) * 256 + tid;
    if (m < NN) {
      int c = labels_idx[m];
      int pos = atomicAdd(&cnt[c * CSTRIDE], 1);
      if (pos < SLOT) {
        st_wc2((float*)&ei[(size_t)c * SLOT + pos], ent_in[m], __int_as_float(m));
      }
    }
  }
  gsync(cnt, 2, grp, leader);

  // ---- Phase 2.5: MALL warm of supports_in — ALL 512 blocks (2/CU on all
  // ---- 256 CUs, 8 waves/CU = the m13 full-BW configuration). R10 proved the
  // ---- consumer-side win (B1 2x faster) but warmed at 1 block/CU = 2.4 TB/s;
  // ---- this placement streams 103 MB at ~6 TB/s (~17 us). No barrier needed:
  // ---- phase 3 below is independent; both drain before gsync(3). ----
  {
    const size_t total4 = (size_t)NN * DD / 4;          // 6,400,000 float4
    const size_t per = total4 / NBLK;                   // 12,500 per block
    size_t lo = (size_t)bid * per;
    size_t hi = lo + per;
    const float4* p4 = (const float4*)supports_in;
    float s0 = 0.f, s1 = 0.f, s2 = 0.f, s3 = 0.f;
    size_t i = lo + tid;
    for (; i + 768 < hi; i += 1024) {                   // 4 loads in flight
      float4 a = p4[i], b = p4[i + 256], c = p4[i + 512], d = p4[i + 768];
      s0 += a.x + a.y + a.z + a.w; s1 += b.x + b.y + b.z + b.w;
      s2 += c.x + c.y + c.z + c.w; s3 += d.x + d.y + d.z + d.w;
    }
    for (; i < hi; i += 256) {
      float4 a = p4[i];
      s0 += a.x + a.y + a.z + a.w;
    }
    s0 += s1 + s2 + s3;
    asm volatile("" :: "v"(s0));                        // sink: keep loads live
  }

  // ---- Phase 3: ppart[s] = z @ Wc^T (512 blocks) ----
  {
    const int ks = bid >> 6;
    gemm_abt_tile(z, Wc, ppart + (size_t)ks * BB * CC, smem, tid,
                  ((bid >> 4) & 3) * 64, (bid & 15) * 64, ks * 64);
  }
  gsync(cnt, 3, grp, leader);

  // ---- Phase 4: rowstats (blocks 0..255); kernel end drains stores ----
  if (bid < BB) {
    float* smv = smem; int* smi = (int*)(smem + 4);
    float* ssm = smem + 8; float* tsm = smem + 12;
    const int b = bid;
    const int lane = tid & 63, wid = tid >> 6;
    const int cbase = tid * 4;
    float rr[4];
    float mv = -INFINITY; int mi = 0x7fffffff;
    if (cbase < CC) {
      float4 v = *(const float4*)&bc[cbase];
#pragma unroll
      for (int s = 0; s < SKP; ++s) {
        float4 pv = *(const float4*)&ppart[(size_t)s * BB * CC + (size_t)b * CC + cbase];
        v.x += pv.x; v.y += pv.y; v.z += pv.z; v.w += pv.w;
      }
      rr[0] = v.x; rr[1] = v.y; rr[2] = v.z; rr[3] = v.w;
#pragma unroll
      for (int j = 0; j < 4; ++j)
        if (rr[j] > mv) { mv = rr[j]; mi = cbase + j; }
    } else { rr[0] = rr[1] = rr[2] = rr[3] = -INFINITY; }
#pragma unroll
    for (int o = 32; o > 0; o >>= 1) {
      float ov = __shfl_down(mv, o, 64);
      int oi = __shfl_down(mi, o, 64);
      if (ov > mv || (ov == mv && oi < mi)) { mv = ov; mi = oi; }
    }
    if (lane == 0) { smv[wid] = mv; smi[wid] = mi; }
    __syncthreads();
    if (tid == 0) {
#pragma unroll
      for (int w = 1; w < 4; ++w)
        if (smv[w] > smv[0] || (smv[w] == smv[0] && smi[w] < smi[0])) {
          smv[0] = smv[w]; smi[0] = smi[w];
        }
    }
    __syncthreads();
    const float m = smv[0]; const int am = smi[0];
    float s = 0.f, t = 0.f;
    if (cbase < CC) {
#pragma unroll
      for (int j = 0; j < 4; ++j) {
        float u = rr[j] - m;
        float e = expf(u);
        s += e; t += u * e;
      }
    }
#pragma unroll
    for (int o = 32; o > 0; o >>= 1) {
      s += __shfl_down(s, o, 64);
      t += __shfl_down(t, o, 64);
    }
    if (lane == 0) { ssm[wid] = s; tsm[wid] = t; }
    __syncthreads();
    if (tid == 0) {
      float S = ssm[0] + ssm[1] + ssm[2] + ssm[3];
      float T = tsm[0] + tsm[1] + tsm[2] + tsm[3];
      float ent = logf(S) - T / S;
      int pos = atomicAdd(&cnt[am * CSTRIDE], 1);
      if (pos < SLOT) {
        st_wc2((float*)&ei[(size_t)am * SLOT + pos], ent, __int_as_float(NN + b));
      }
    }
  }
}

// ========== kernel B1: phase 5 only — 1000 blocks, 4 blocks/CU ==========
__global__ __launch_bounds__(256, 4) void megaB1(
    const float* supports_in, float* ws) {
  __shared__ __align__(16) float smem[SMEM_F];
  float*  z   = ws + Z_OFF;
  int*    cnt = (int*)(ws + CNT_OFF);
  float2* ei  = (float2*)(ws + EI_OFF);
  float*  wn  = ws + WN_OFF;
  do_class(blockIdx.x, threadIdx.x, smem, supports_in, z, ei, cnt, wn);
}

// ========== kernel B2: phase 6 — out = z @ wn^T (256 blocks) ==========
__global__ __launch_bounds__(256, 2) void megaB2(
    float* out, float* ws) {
  __shared__ __align__(16) float smem[16 * 20 + 16 * 68];
  float* z  = ws + Z_OFF;
  float* wn = ws + WN_OFF;
  const int bid = blockIdx.x, tid = threadIdx.x;
  float (*As)[20] = (float(*)[20])smem;
  float (*Bs)[68] = (float(*)[68])(smem + 16 * 20);
  const int m0 = (bid >> 4) * 16;
  const int n0 = (bid & 15) * 64;
  const int arow = tid >> 4, ak = tid & 15;
  const int br = tid >> 2, bcl = (tid & 3) * 4;
  const int tr = tid >> 4, tn4 = (tid & 15) * 4;
  float acc[4] = {};
  float av = z[(size_t)(m0 + arow) * DD + ak];
  float4 bv = make_float4(0.f, 0.f, 0.f, 0.f);
  if (n0 + br < CC) bv = *(const float4*)&wn[(size_t)(n0 + br) * DD + bcl];
  for (int k0 = 0; k0 < DD; k0 += 16) {
    __syncthreads();
    As[ak][arow] = av;
    Bs[bcl + 0][br] = bv.x; Bs[bcl + 1][br] = bv.y;
    Bs[bcl + 2][br] = bv.z; Bs[bcl + 3][br] = bv.w;
    __syncthreads();
    if (k0 + 16 < DD) {
      av = z[(size_t)(m0 + arow) * DD + k0 + 16 + ak];
      if (n0 + br < CC)
        bv = *(const float4*)&wn[(size_t)(n0 + br) * DD + k0 + 16 + bcl];
    }
#pragma unroll
    for (int q = 0; q < 16; ++q) {
      float a = As[q][tr];
      float4 b = *(const float4*)&Bs[q][tn4];
      acc[0] += a * b.x; acc[1] += a * b.y;
      acc[2] += a * b.z; acc[3] += a * b.w;
    }
  }
  int n = n0 + tn4;
  if (n + 3 < CC) {
    *(float4*)&out[(size_t)(m0 + tr) * CC + n] =
        make_float4(acc[0], acc[1], acc[2], acc[3]);
  } else {
#pragma unroll
    for (int j = 0; j < 4; ++j)
      if (n + j < CC) out[(size_t)(m0 + tr) * CC + n + j] = acc[j];
  }
}

// ============================ launcher ===================================
extern "C" void kernel_launch(void* const* d_in, const int* in_sizes, int n_in,
                              void* d_out, int out_size, void* d_ws, size_t ws_size,
                              hipStream_t stream) {
  (void)in_sizes; (void)n_in; (void)out_size; (void)ws_size;
  const float* x           = (const float*)d_in[0];
  const float* Wf          = (const float*)d_in[1];
  const float* Wc          = (const float*)d_in[2];
  const float* bc          = (const float*)d_in[3];
  const float* supports_in = (const float*)d_in[4];
  const float* ent_in      = (const float*)d_in[5];
  const int*   labels_idx  = (const int*)d_in[6];
  float* out = (float*)d_out;
  float* W = (float*)d_ws;
  int* cnt = (int*)(W + CNT_OFF);

  // zero class counters (64 KB) + 4KB-spaced barrier pages (80 KB)
  hipMemsetAsync(cnt, 0, CNT_INTS * sizeof(int), stream);
  // A: phases 1-4; phase 2.5 MALL-warms supports at full occupancy
  hipLaunchKernelGGL(megaA, dim3(NBLK), dim3(256), 0, stream,
                     x, Wf, Wc, bc, supports_in, ent_in, labels_idx, W);
  // B1: phase 5 at 1 block/class, 4 blocks/CU (gather hits MALL)
  hipLaunchKernelGGL(megaB1, dim3(CC), dim3(256), 0, stream, supports_in, W);
  // B2: phase 6
  hipLaunchKernelGGL(megaB2, dim3(256), dim3(256), 0, stream, out, W);
}

// Round 13
// 212.694 us; speedup vs baseline: 1.1044x; 1.1044x over previous
//
#include <hip/hip_runtime.h>
#include <math.h>

// Problem constants (fixed by setup_inputs)
#define BB   256
#define DIN  2048
#define DD   512
#define CC   1000
#define NN   50000
#define FILTER_K 100
#define SLOT 512           // per-class capacity; max real ~90 old + <=256 new
#define CSTRIDE 16         // one counter per 64B cacheline (atomic contention)

#define SK1  32            // split-K for z = x@Wf  (klen 64)
#define SKP  8             // split-K for p = z@Wc^T (klen 64)
#define SKO  8             // split-K for out = z@wn^T (klen 64)
#define NBLK 512           // megaA grid: 2 blocks/CU, guaranteed resident
#define NGRP 8             // barrier arrival groups (two-level barrier)
#define GSZ  (NBLK / NGRP) // 64 blocks per group

// ---------------- workspace layout (float elements) ----------------
#define Z_OFF     0                          // z:     [256][512]
#define CNT_OFF   (Z_OFF + BB*DD)            // cnt:   [1024*16] int (strided)
#define BAR_BASE  16384                      // int offset within cnt region
#define ARR_IDX(g)   (BAR_BASE + (g)*1024)          // arrival counters, 8 pages
#define GFLG_IDX(g)  (BAR_BASE + (8+(g))*1024)      // per-group flags, 8 pages
#define GLBC_IDX     (BAR_BASE + 16*1024)           // global counter
#define GLBF_IDX     (BAR_BASE + 17*1024)           // global flag
#define CNT_INTS  (16384 + 20*1024)          // 36864 ints memset'd
#define EI_OFF    (CNT_OFF + CNT_INTS)       // ei:    [1000][512] float2 (ent,idx)
#define WN_OFF    (EI_OFF + CC*SLOT*2)       // wn:    [1000][512]
#define ZP_OFF    (WN_OFF + CC*DD)           // zpart: [32][256][512]
#define PP_OFF    (ZP_OFF + SK1*BB*DD)       // ppart: [8][256][1000]
#define OP_OFF    (PP_OFF + SKP*BB*CC)       // opart: [8][256][1000] (fresh region)

#define SMEM_F 3712        // 14848 B shared overlay (max phase = class_weights 3588)

// ---- MALL-coherent (write-through) stores for cross-phase intermediates ----
typedef float f32x4 __attribute__((ext_vector_type(4)));
typedef float f32x2 __attribute__((ext_vector_type(2)));

__device__ __forceinline__ void st_wc4(float* p, float4 v) {
  f32x4 w = {v.x, v.y, v.z, v.w};
  asm volatile("global_store_dwordx4 %0, %1, off sc0 sc1" :: "v"(p), "v"(w) : "memory");
}
__device__ __forceinline__ void st_wc2(float* p, float a, float b) {
  f32x2 w = {a, b};
  asm volatile("global_store_dwordx2 %0, %1, off sc0 sc1" :: "v"(p), "v"(w) : "memory");
}
__device__ __forceinline__ void st_wc1(float* p, float a) {
  asm volatile("global_store_dword %0, %1, off sc0 sc1" :: "v"(p), "v"(a) : "memory");
}
// coherent 8B load (ei is written in two phases; bypass L1/L2)
__device__ __forceinline__ float2 ld_cv2(const float2* p) {
  unsigned long long r = __hip_atomic_load((const unsigned long long*)p,
      __ATOMIC_RELAXED, __HIP_MEMORY_SCOPE_AGENT);
  float2 o;
  o.x = __uint_as_float((unsigned)(r & 0xffffffffULL));
  o.y = __uint_as_float((unsigned)(r >> 32));
  return o;
}
__device__ __forceinline__ int ld_ci(const int* p) {
  return __hip_atomic_load(p, __ATOMIC_RELAXED, __HIP_MEMORY_SCOPE_AGENT);
}

// ---- device-wide sense barrier (used only inside megaA, epochs 1..3) ----
__device__ __forceinline__ void gsync(int* cnt, int epoch, int grp, bool leader) {
  asm volatile("s_waitcnt vmcnt(0) lgkmcnt(0)" ::: "memory");
  __syncthreads();
  if (threadIdx.x == 0) {
    int t = __hip_atomic_fetch_add(&cnt[ARR_IDX(grp)], 1, __ATOMIC_RELAXED,
                                   __HIP_MEMORY_SCOPE_AGENT);
    if (t == epoch * GSZ - 1) {
      int u = __hip_atomic_fetch_add(&cnt[GLBC_IDX], 1, __ATOMIC_RELAXED,
                                     __HIP_MEMORY_SCOPE_AGENT);
      if (u == epoch * NGRP - 1)
        __hip_atomic_store(&cnt[GLBF_IDX], epoch, __ATOMIC_RELAXED,
                           __HIP_MEMORY_SCOPE_AGENT);
    }
    if (leader) {
      while (__hip_atomic_load(&cnt[GLBF_IDX], __ATOMIC_RELAXED,
                               __HIP_MEMORY_SCOPE_AGENT) < epoch)
        __builtin_amdgcn_s_sleep(4);
      __hip_atomic_store(&cnt[GFLG_IDX(grp)], epoch, __ATOMIC_RELAXED,
                         __HIP_MEMORY_SCOPE_AGENT);
    } else {
      while (__hip_atomic_load(&cnt[GFLG_IDX(grp)], __ATOMIC_RELAXED,
                               __HIP_MEMORY_SCOPE_AGENT) < epoch)
        __builtin_amdgcn_s_sleep(8);
    }
  }
  __syncthreads();
}

// ---- per-class select-K + normalized row-sum + column norm ----
// Gather loads are NON-TEMPORAL: each supports line is read exactly once per
// iteration, and nt avoids evict-writeback of the 400MB fill's dirty MALL
// lines on allocation (the R10/R11-measured ~1B-writeback-per-byte-read tax).
__device__ __forceinline__ void do_class(
    int c, int tid, float* smem, const float* supports_in, const float* z,
    const float2* ei, const int* cnt, float* wn) {
  int*   sel = (int*)smem;                       // [512]
  float* se  = smem + SLOT;                      // [512]
  int*   si  = (int*)(smem + 2*SLOT);            // [512]
  float (*part)[DD] = (float(*)[DD])(smem + 3*SLOT);  // [4][512]
  float* tot = smem + 3*SLOT + 4*DD;             // [4]
  const int lane = tid & 63, wid = tid >> 6;
  int n = ld_ci(&cnt[c * CSTRIDE]); if (n > SLOT) n = SLOT;

  int seln;
  if (n <= FILTER_K) {
    seln = n;
    for (int i = tid; i < n; i += 256)
      sel[i] = __float_as_int(ld_cv2(&ei[(size_t)c * SLOT + i]).y);
  } else {
    for (int i = tid; i < SLOT; i += 256) {
      if (i < n) {
        float2 pr = ld_cv2(&ei[(size_t)c * SLOT + i]);
        se[i] = pr.x; si[i] = __float_as_int(pr.y);
      } else { se[i] = INFINITY; si[i] = 0x7fffffff; }
    }
    __syncthreads();
    for (int k = 2; k <= SLOT; k <<= 1)
      for (int j = k >> 1; j > 0; j >>= 1) {
        for (int i = tid; i < SLOT; i += 256) {
          int ixj = i ^ j;
          if (ixj > i) {
            bool up = ((i & k) == 0);
            float e1 = se[i], e2 = se[ixj];
            int i1 = si[i], i2 = si[ixj];
            bool gt = (e1 > e2) || (e1 == e2 && i1 > i2);
            if (gt == up) { se[i] = e2; se[ixj] = e1; si[i] = i2; si[ixj] = i1; }
          }
        }
        __syncthreads();
      }
    seln = FILTER_K;
    for (int i = tid; i < FILTER_K; i += 256) sel[i] = si[i];
  }
  __syncthreads();
  const int seln_pad = (seln + 15) & ~15;
  if (seln > 0)
    for (int i = seln + tid; i < seln_pad; i += 256) sel[i] = sel[0];
  __syncthreads();

  f32x4 a0 = {0.f, 0.f, 0.f, 0.f}, a1 = {0.f, 0.f, 0.f, 0.f};
  for (int t = wid * 4; t < seln_pad; t += 16) {
    f32x4 u0[4], u1[4]; float s[4];
#pragma unroll
    for (int j = 0; j < 4; ++j) {
      int r = sel[t + j];
      const f32x4* p4 = (const f32x4*)((r < NN)
          ? supports_in + (size_t)r * DD : z + (size_t)(r - NN) * DD);
      u0[j] = __builtin_nontemporal_load(p4 + lane * 2);
      u1[j] = __builtin_nontemporal_load(p4 + lane * 2 + 1);
    }
#pragma unroll
    for (int j = 0; j < 4; ++j)
      s[j] = u0[j][0] * u0[j][0] + u0[j][1] * u0[j][1] + u0[j][2] * u0[j][2]
           + u0[j][3] * u0[j][3] + u1[j][0] * u1[j][0] + u1[j][1] * u1[j][1]
           + u1[j][2] * u1[j][2] + u1[j][3] * u1[j][3];
#pragma unroll
    for (int o = 1; o < 64; o <<= 1) {
#pragma unroll
      for (int j = 0; j < 4; ++j) s[j] += __shfl_xor(s[j], o, 64);
    }
#pragma unroll
    for (int j = 0; j < 4; ++j) {
      float sc = (t + j < seln) ? 1.0f / fmaxf(sqrtf(s[j]), 1e-12f) : 0.f;
      a0 += u0[j] * sc;
      a1 += u1[j] * sc;
    }
  }

  *(f32x4*)&part[wid][lane * 8] = a0;
  *(f32x4*)&part[wid][lane * 8 + 4] = a1;
  __syncthreads();
  const int d = tid * 2;
  float wx = part[0][d] + part[1][d] + part[2][d] + part[3][d];
  float wy = part[0][d + 1] + part[1][d + 1] + part[2][d + 1] + part[3][d + 1];
  float ss = wx * wx + wy * wy;
#pragma unroll
  for (int o = 1; o < 64; o <<= 1) ss += __shfl_xor(ss, o, 64);
  if (lane == 0) tot[wid] = ss;
  __syncthreads();
  float S = tot[0] + tot[1] + tot[2] + tot[3];
  float sc = 1.0f / fmaxf(sqrtf(S), 1e-12f);
  st_wc2(wn + (size_t)c * DD + 2 * tid, wx * sc, wy * sc);
}

// ---- 64x64 split-K A@B^T tile body (phases 3 and B2a; R6/R8-verified) ----
__device__ __forceinline__ void gemm_abt_tile(
    const float* __restrict__ A, const float* __restrict__ Bm,
    float* __restrict__ Cb, float* smem, int tid, int m0, int n0, int k0) {
  float (*As)[68] = (float(*)[68])smem;
  float (*Bs)[68] = (float(*)[68])(smem + 16 * 68);
  const int ar = tid >> 2, ac = (tid & 3) * 4;
  const int tm = (tid >> 4) * 4, tn = (tid & 15) * 4;
  float acc[4][4] = {};
  float4 av = *(const float4*)&A[(size_t)(m0 + ar) * DD + k0 + ac];
  float4 bv = make_float4(0.f, 0.f, 0.f, 0.f);
  if (n0 + ar < CC) bv = *(const float4*)&Bm[(size_t)(n0 + ar) * DD + k0 + ac];
  for (int kk = 0; kk < 64; kk += 16) {
    __syncthreads();
    As[ac + 0][ar] = av.x; As[ac + 1][ar] = av.y;
    As[ac + 2][ar] = av.z; As[ac + 3][ar] = av.w;
    Bs[ac + 0][ar] = bv.x; Bs[ac + 1][ar] = bv.y;
    Bs[ac + 2][ar] = bv.z; Bs[ac + 3][ar] = bv.w;
    __syncthreads();
    if (kk + 16 < 64) {
      av = *(const float4*)&A[(size_t)(m0 + ar) * DD + k0 + kk + 16 + ac];
      if (n0 + ar < CC)
        bv = *(const float4*)&Bm[(size_t)(n0 + ar) * DD + k0 + kk + 16 + ac];
    }
#pragma unroll
    for (int q = 0; q < 16; ++q) {
      float4 a = *(const float4*)&As[q][tm];
      float4 b = *(const float4*)&Bs[q][tn];
      float aa[4] = {a.x, a.y, a.z, a.w};
      float bb[4] = {b.x, b.y, b.z, b.w};
#pragma unroll
      for (int i = 0; i < 4; ++i)
#pragma unroll
        for (int j = 0; j < 4; ++j) acc[i][j] += aa[i] * bb[j];
    }
  }
#pragma unroll
  for (int i = 0; i < 4; ++i) {
    int n = n0 + tn;
    if (n + 3 < CC) {
      st_wc4(&Cb[(size_t)(m0 + tm + i) * CC + n],
             make_float4(acc[i][0], acc[i][1], acc[i][2], acc[i][3]));
    } else {
#pragma unroll
      for (int j = 0; j < 4; ++j)
        if (n + j < CC) st_wc1(&Cb[(size_t)(m0 + tm + i) * CC + n + j], acc[i][j]);
    }
  }
}

// ========== kernel A: phases 1-4 (R8-exact; NO warm) ==========
__global__ __launch_bounds__(256, 2) void megaA(
    const float* x, const float* Wf, const float* Wc, const float* bc,
    const float* ent_in, const int* labels_idx, float* ws) {
  __shared__ __align__(16) float smem[SMEM_F];
  float*  z     = ws + Z_OFF;
  int*    cnt   = (int*)(ws + CNT_OFF);
  float2* ei    = (float2*)(ws + EI_OFF);
  float*  zpart = ws + ZP_OFF;
  float*  ppart = ws + PP_OFF;
  const int bid = blockIdx.x, tid = threadIdx.x;
  const int grp = bid >> 6;
  const bool leader = (bid & 63) == 0;

  // ---- Phase 1: zpart = x@Wf split-K, ALL 512 blocks (SK1=32, klen=64) ----
  {
    float (*As)[68]  = (float(*)[68])smem;
    float (*Bs)[132] = (float(*)[132])(smem + 16 * 68);
    const int m0 = ((bid >> 2) & 3) * 64;
    const int n0 = (bid & 3) * 128;
    const int k0 = (bid >> 4) * 64;
    const int ar = tid >> 2, ac = (tid & 3) * 4;
    const int br = tid >> 4, bcn = (tid & 15) * 8;
    const int tm = (tid >> 4) * 4, tn = (tid & 15) * 4;
    float acc[4][8] = {};
    float4 av  = *(const float4*)&x[(size_t)(m0 + ar) * DIN + k0 + ac];
    float4 bv0 = *(const float4*)&Wf[(size_t)(k0 + br) * DD + n0 + bcn];
    float4 bv1 = *(const float4*)&Wf[(size_t)(k0 + br) * DD + n0 + bcn + 4];
    for (int kk = 0; kk < 64; kk += 16) {
      __syncthreads();
      As[ac + 0][ar] = av.x; As[ac + 1][ar] = av.y;
      As[ac + 2][ar] = av.z; As[ac + 3][ar] = av.w;
      *(float4*)&Bs[br][bcn] = bv0;
      *(float4*)&Bs[br][bcn + 4] = bv1;
      __syncthreads();
      if (kk + 16 < 64) {
        av  = *(const float4*)&x[(size_t)(m0 + ar) * DIN + k0 + kk + 16 + ac];
        bv0 = *(const float4*)&Wf[(size_t)(k0 + kk + 16 + br) * DD + n0 + bcn];
        bv1 = *(const float4*)&Wf[(size_t)(k0 + kk + 16 + br) * DD + n0 + bcn + 4];
      }
#pragma unroll
      for (int q = 0; q < 16; ++q) {
        float4 a  = *(const float4*)&As[q][tm];
        float4 b0 = *(const float4*)&Bs[q][tn];
        float4 b1 = *(const float4*)&Bs[q][tn + 64];
        float aa[4] = {a.x, a.y, a.z, a.w};
        float bb[8] = {b0.x, b0.y, b0.z, b0.w, b1.x, b1.y, b1.z, b1.w};
#pragma unroll
        for (int i = 0; i < 4; ++i)
#pragma unroll
          for (int j = 0; j < 8; ++j) acc[i][j] += aa[i] * bb[j];
      }
    }
    float* Cb = zpart + (size_t)(bid >> 4) * BB * DD;
#pragma unroll
    for (int i = 0; i < 4; ++i) {
      st_wc4(&Cb[(size_t)(m0 + tm + i) * DD + n0 + tn],
             make_float4(acc[i][0], acc[i][1], acc[i][2], acc[i][3]));
      st_wc4(&Cb[(size_t)(m0 + tm + i) * DD + n0 + 64 + tn],
             make_float4(acc[i][4], acc[i][5], acc[i][6], acc[i][7]));
    }
  }
  gsync(cnt, 1, grp, leader);

  // ---- Phase 2: z reduce (0..127) | old-row scatter (128..323) ----
  if (bid < 128) {
    const int n4 = BB * DD / 4;
    int i = bid * 256 + tid;
    if (i < n4) {
      const float4* p4 = (const float4*)zpart;
      float4 a = p4[i];
#pragma unroll
      for (int s = 1; s < SK1; ++s) {
        float4 b = p4[(size_t)s * n4 + i];
        a.x += b.x; a.y += b.y; a.z += b.z; a.w += b.w;
      }
      st_wc4(z + 4 * (size_t)i, a);
    }
  } else if (bid < 324) {
    int m = (bid - 128) * 256 + tid;
    if (m < NN) {
      int c = labels_idx[m];
      int pos = atomicAdd(&cnt[c * CSTRIDE], 1);
      if (pos < SLOT) {
        st_wc2((float*)&ei[(size_t)c * SLOT + pos], ent_in[m], __int_as_float(m));
      }
    }
  }
  gsync(cnt, 2, grp, leader);

  // ---- Phase 3: ppart[s] = z @ Wc^T (512 blocks) ----
  {
    const int ks = bid >> 6;
    gemm_abt_tile(z, Wc, ppart + (size_t)ks * BB * CC, smem, tid,
                  ((bid >> 4) & 3) * 64, (bid & 15) * 64, ks * 64);
  }
  gsync(cnt, 3, grp, leader);

  // ---- Phase 4: rowstats (blocks 0..255); kernel end drains stores ----
  if (bid < BB) {
    float* smv = smem; int* smi = (int*)(smem + 4);
    float* ssm = smem + 8; float* tsm = smem + 12;
    const int b = bid;
    const int lane = tid & 63, wid = tid >> 6;
    const int cbase = tid * 4;
    float rr[4];
    float mv = -INFINITY; int mi = 0x7fffffff;
    if (cbase < CC) {
      float4 v = *(const float4*)&bc[cbase];
#pragma unroll
      for (int s = 0; s < SKP; ++s) {
        float4 pv = *(const float4*)&ppart[(size_t)s * BB * CC + (size_t)b * CC + cbase];
        v.x += pv.x; v.y += pv.y; v.z += pv.z; v.w += pv.w;
      }
      rr[0] = v.x; rr[1] = v.y; rr[2] = v.z; rr[3] = v.w;
#pragma unroll
      for (int j = 0; j < 4; ++j)
        if (rr[j] > mv) { mv = rr[j]; mi = cbase + j; }
    } else { rr[0] = rr[1] = rr[2] = rr[3] = -INFINITY; }
#pragma unroll
    for (int o = 32; o > 0; o >>= 1) {
      float ov = __shfl_down(mv, o, 64);
      int oi = __shfl_down(mi, o, 64);
      if (ov > mv || (ov == mv && oi < mi)) { mv = ov; mi = oi; }
    }
    if (lane == 0) { smv[wid] = mv; smi[wid] = mi; }
    __syncthreads();
    if (tid == 0) {
#pragma unroll
      for (int w = 1; w < 4; ++w)
        if (smv[w] > smv[0] || (smv[w] == smv[0] && smi[w] < smi[0])) {
          smv[0] = smv[w]; smi[0] = smi[w];
        }
    }
    __syncthreads();
    const float m = smv[0]; const int am = smi[0];
    float s = 0.f, t = 0.f;
    if (cbase < CC) {
#pragma unroll
      for (int j = 0; j < 4; ++j) {
        float u = rr[j] - m;
        float e = expf(u);
        s += e; t += u * e;
      }
    }
#pragma unroll
    for (int o = 32; o > 0; o >>= 1) {
      s += __shfl_down(s, o, 64);
      t += __shfl_down(t, o, 64);
    }
    if (lane == 0) { ssm[wid] = s; tsm[wid] = t; }
    __syncthreads();
    if (tid == 0) {
      float S = ssm[0] + ssm[1] + ssm[2] + ssm[3];
      float T = tsm[0] + tsm[1] + tsm[2] + tsm[3];
      float ent = logf(S) - T / S;
      int pos = atomicAdd(&cnt[am * CSTRIDE], 1);
      if (pos < SLOT) {
        st_wc2((float*)&ei[(size_t)am * SLOT + pos], ent, __int_as_float(NN + b));
      }
    }
  }
}

// ========== kernel B1: phase 5 — 1000 blocks, nt gather ==========
__global__ __launch_bounds__(256, 4) void megaB1(
    const float* supports_in, float* ws) {
  __shared__ __align__(16) float smem[SMEM_F];
  float*  z   = ws + Z_OFF;
  int*    cnt = (int*)(ws + CNT_OFF);
  float2* ei  = (float2*)(ws + EI_OFF);
  float*  wn  = ws + WN_OFF;
  do_class(blockIdx.x, threadIdx.x, smem, supports_in, z, ei, cnt, wn);
}

// ========== kernel B2a: opart[s] = z @ wn^T (512 blocks, split-K) ==========
__global__ __launch_bounds__(256, 2) void megaB2a(float* ws) {
  __shared__ __align__(16) float smem[2 * 16 * 68];
  float* z     = ws + Z_OFF;
  float* wn    = ws + WN_OFF;
  float* opart = ws + OP_OFF;
  const int bid = blockIdx.x, tid = threadIdx.x;
  const int ks = bid >> 6;            // 0..7
  gemm_abt_tile(z, wn, opart + (size_t)ks * BB * CC, smem, tid,
                ((bid >> 4) & 3) * 64, (bid & 15) * 64, ks * 64);
}

// ========== kernel B2b: out = sum of 8 opart partials (256 blocks) ==========
__global__ __launch_bounds__(256) void megaB2b(float* out, float* ws) {
  float* opart = ws + OP_OFF;
  const int bid = blockIdx.x, tid = threadIdx.x;
  const int cbase = tid * 4;          // 1000/4 = 250 threads active
  if (cbase < CC) {
    float4 a = *(const float4*)&opart[(size_t)bid * CC + cbase];
#pragma unroll
    for (int s = 1; s < SKO; ++s) {
      float4 b = *(const float4*)&opart[(size_t)s * BB * CC + (size_t)bid * CC + cbase];
      a.x += b.x; a.y += b.y; a.z += b.z; a.w += b.w;
    }
    *(float4*)&out[(size_t)bid * CC + cbase] = a;   // final output: normal store
  }
}

// ============================ launcher ===================================
extern "C" void kernel_launch(void* const* d_in, const int* in_sizes, int n_in,
                              void* d_out, int out_size, void* d_ws, size_t ws_size,
                              hipStream_t stream) {
  (void)in_sizes; (void)n_in; (void)out_size; (void)ws_size;
  const float* x           = (const float*)d_in[0];
  const float* Wf          = (const float*)d_in[1];
  const float* Wc          = (const float*)d_in[2];
  const float* bc          = (const float*)d_in[3];
  const float* supports_in = (const float*)d_in[4];
  const float* ent_in      = (const float*)d_in[5];
  const int*   labels_idx  = (const int*)d_in[6];
  float* out = (float*)d_out;
  float* W = (float*)d_ws;
  int* cnt = (int*)(W + CNT_OFF);

  // zero class counters (64 KB) + 4KB-spaced barrier pages (80 KB)
  hipMemsetAsync(cnt, 0, CNT_INTS * sizeof(int), stream);
  // A: phases 1-4 (barriered persistent grid; R8-exact, no warm)
  hipLaunchKernelGGL(megaA, dim3(NBLK), dim3(256), 0, stream,
                     x, Wf, Wc, bc, ent_in, labels_idx, W);
  // B1: phase 5 (nt gather — no MALL allocation, no dirty-fill writeback tax)
  hipLaunchKernelGGL(megaB1, dim3(CC), dim3(256), 0, stream, supports_in, W);
  // B2: phase 6 split-K + reduce
  hipLaunchKernelGGL(megaB2a, dim3(NBLK), dim3(256), 0, stream, W);
  hipLaunchKernelGGL(megaB2b, dim3(256), dim3(256), 0, stream, out, W);
}